// Round 1
// baseline (330.039 us; speedup 1.0000x reference)
//
#include <hip/hip_runtime.h>
#include <hip/hip_bf16.h>
#include <math.h>

// Problem constants
#define B_ 2
#define S_ 2048
#define D_ 1024
#define H_ 16
#define DH 64
#define NTOK 4096   // B_*S_

typedef __bf16 bf16_t;
typedef __bf16 bf16x8 __attribute__((ext_vector_type(8)));
typedef float floatx4 __attribute__((ext_vector_type(4)));

// ---------------------------------------------------------------------------
// Kernel 0: fp32 -> bf16 conversion of query + all 4 weight matrices.
// Layout in ws: Xbf[4096*1024] | Wqkv[3*1024*1024] | Wo[1024*1024]
// ---------------------------------------------------------------------------
__global__ __launch_bounds__(256) void convert_kernel(
    const float* __restrict__ query, const float* __restrict__ Wq,
    const float* __restrict__ Wk, const float* __restrict__ Wv,
    const float* __restrict__ Wo, bf16_t* __restrict__ Xbf,
    bf16_t* __restrict__ Wqkv, bf16_t* __restrict__ Wobf) {
  long base = ((long)blockIdx.x * 256 + threadIdx.x) * 4;
  const float* src;
  bf16_t* dst;
  long off;
  if (base < 4194304L)      { src = query; dst = Xbf;             off = base; }
  else if (base < 5242880L) { src = Wq;    dst = Wqkv;            off = base - 4194304L; }
  else if (base < 6291456L) { src = Wk;    dst = Wqkv + 1048576;  off = base - 5242880L; }
  else if (base < 7340032L) { src = Wv;    dst = Wqkv + 2097152;  off = base - 6291456L; }
  else                      { src = Wo;    dst = Wobf;            off = base - 7340032L; }
  float4 v = *reinterpret_cast<const float4*>(src + off);
  dst[off + 0] = (bf16_t)v.x;
  dst[off + 1] = (bf16_t)v.y;
  dst[off + 2] = (bf16_t)v.z;
  dst[off + 3] = (bf16_t)v.w;
}

// ---------------------------------------------------------------------------
// Shared 128x128 bf16 MFMA GEMM tile: C[m][n] = sum_k A[m][k] * Bn[n][k]
// (Bn is torch-Linear weight layout [out][in] == B-operand natural layout.)
// Block = 256 threads = 4 waves in 2x2; each wave 64x64 = 4x4 16x16 frags.
// LDS row stride 40 bf16 (80B): 16B-aligned rows, frag reads 2-way conflict
// only (free per m136).
// ---------------------------------------------------------------------------
__device__ __forceinline__ void gemm_tile_128(const bf16_t* __restrict__ A,
                                              const bf16_t* __restrict__ Bn,
                                              int m0, int n0,
                                              floatx4 acc[4][4]) {
  __shared__ __align__(16) bf16_t As[128][40];
  __shared__ __align__(16) bf16_t Bs[128][40];
  const int tid = threadIdx.x;
  const int lane = tid & 63;
  const int wave = tid >> 6;
  const int wm = (wave >> 1) * 64;
  const int wn = (wave & 1) * 64;
  const int lr = lane & 15;
  const int lq = lane >> 4;

  for (int kk = 0; kk < 1024; kk += 32) {
    __syncthreads();
#pragma unroll
    for (int u = 0; u < 2; u++) {
      int uu = tid + u * 256;
      int row = uu >> 2;
      int c = (uu & 3) * 8;
      *reinterpret_cast<float4*>(&As[row][c]) =
          *reinterpret_cast<const float4*>(A + (size_t)(m0 + row) * 1024 + kk + c);
      *reinterpret_cast<float4*>(&Bs[row][c]) =
          *reinterpret_cast<const float4*>(Bn + (size_t)(n0 + row) * 1024 + kk + c);
    }
    __syncthreads();
    bf16x8 af[4], bfr[4];
#pragma unroll
    for (int i = 0; i < 4; i++)
      af[i] = *reinterpret_cast<const bf16x8*>(&As[wm + i * 16 + lr][lq * 8]);
#pragma unroll
    for (int j = 0; j < 4; j++)
      bfr[j] = *reinterpret_cast<const bf16x8*>(&Bs[wn + j * 16 + lr][lq * 8]);
#pragma unroll
    for (int i = 0; i < 4; i++)
#pragma unroll
      for (int j = 0; j < 4; j++)
        acc[i][j] = __builtin_amdgcn_mfma_f32_16x16x32_bf16(af[i], bfr[j],
                                                            acc[i][j], 0, 0, 0);
  }
}

// ---------------------------------------------------------------------------
// Kernel 1: QKV projection. z = 0/1/2 selects Q/K/V.
// Q,K written (bias added, pre-RoPE) to [B,H,S,dh] bf16.
// V written transposed to Vt [B,H,dh,S] bf16 (for PV B-operand).
// ---------------------------------------------------------------------------
__global__ __launch_bounds__(256) void qkv_kernel(
    const bf16_t* __restrict__ Xbf, const bf16_t* __restrict__ Wqkv,
    const float* __restrict__ bq, const float* __restrict__ bk,
    const float* __restrict__ bv, bf16_t* __restrict__ Qbuf,
    bf16_t* __restrict__ Kbuf, bf16_t* __restrict__ Vt) {
  const int m0 = blockIdx.x * 128;
  const int n0 = blockIdx.y * 128;
  const int z = blockIdx.z;
  floatx4 acc[4][4];
  floatx4 zero4 = {0.f, 0.f, 0.f, 0.f};
#pragma unroll
  for (int i = 0; i < 4; i++)
#pragma unroll
    for (int j = 0; j < 4; j++) acc[i][j] = zero4;

  gemm_tile_128(Xbf, Wqkv + (size_t)z * 1048576, m0, n0, acc);

  const float* bias = (z == 0) ? bq : ((z == 1) ? bk : bv);
  const int lane = threadIdx.x & 63;
  const int wave = threadIdx.x >> 6;
  const int wm = (wave >> 1) * 64;
  const int wn = (wave & 1) * 64;
  const int lr = lane & 15;
  const int lq = lane >> 4;

#pragma unroll
  for (int i = 0; i < 4; i++)
#pragma unroll
    for (int j = 0; j < 4; j++)
#pragma unroll
      for (int r = 0; r < 4; r++) {
        int m = m0 + wm + i * 16 + lq * 4 + r;  // token index
        int n = n0 + wn + j * 16 + lr;          // feature index
        float v = acc[i][j][r] + bias[n];
        int b = m >> 11, s = m & 2047;
        int h = n >> 6, d = n & 63;
        if (z == 0)
          Qbuf[(((size_t)(b * 16 + h) * 2048 + s) << 6) + d] = (bf16_t)v;
        else if (z == 1)
          Kbuf[(((size_t)(b * 16 + h) * 2048 + s) << 6) + d] = (bf16_t)v;
        else
          Vt[((size_t)(b * 16 + h) * 64 + d) * 2048 + s] = (bf16_t)v;
      }
}

// ---------------------------------------------------------------------------
// Kernel 2: RoPE in place on Q and K ([B,H,S,dh] bf16).
// Pair (p, p+32), angle = s * 10000^(-p/32).
// ---------------------------------------------------------------------------
__global__ __launch_bounds__(256) void rope_kernel(bf16_t* __restrict__ Qbuf,
                                                   bf16_t* __restrict__ Kbuf) {
  int idx = blockIdx.x * 256 + threadIdx.x;  // [0, 4M)
  bf16_t* buf = (idx & (1 << 21)) ? Kbuf : Qbuf;
  int r = idx & ((1 << 21) - 1);
  int p = r & 31;
  int srow = (r >> 5) & 2047;
  int bh = r >> 16;
  size_t base = ((size_t)bh * 2048 + srow) * 64 + p;
  // ln(10000)/32 = 0.28782313662425576
  float inv = __expf(-(float)p * 0.28782313662425576f);
  float ang = (float)srow * inv;
  float c, sn;
  sincosf(ang, &sn, &c);
  float x1 = (float)buf[base];
  float x2 = (float)buf[base + 32];
  buf[base] = (bf16_t)(x1 * c - x2 * sn);
  buf[base + 32] = (bf16_t)(x2 * c + x1 * sn);
}

// ---------------------------------------------------------------------------
// Kernel 3: flash attention. Block: (q-tile of 64, one bh). 4 waves, each
// owns 16 q-rows. Key tiles of 128. Online softmax; P goes through LDS to
// convert MFMA C-layout -> A-layout. Output to Ctx [B,S,H*dh] bf16.
// ---------------------------------------------------------------------------
__global__ __launch_bounds__(256) void attn_kernel(
    const bf16_t* __restrict__ Qbuf, const bf16_t* __restrict__ Kbuf,
    const bf16_t* __restrict__ Vt, bf16_t* __restrict__ Ctx) {
  __shared__ __align__(16) bf16_t Qs[64][72];
  __shared__ __align__(16) bf16_t Ks[128][72];
  __shared__ __align__(16) bf16_t Vs[64][136];     // [d][key]
  __shared__ __align__(16) bf16_t Ps[4][16][136];  // per-wave P
  const int tid = threadIdx.x;
  const int lane = tid & 63;
  const int w = tid >> 6;
  const int lr = lane & 15;
  const int lq = lane >> 4;
  const int q0 = blockIdx.x * 64;
  const int bh = blockIdx.y;
  const size_t hb = (size_t)bh * 2048 * 64;

  // stage Q tile [64][64]
  for (int u = tid; u < 512; u += 256) {
    int row = u >> 3;
    int c = (u & 7) * 8;
    *reinterpret_cast<float4*>(&Qs[row][c]) =
        *reinterpret_cast<const float4*>(Qbuf + hb + (size_t)(q0 + row) * 64 + c);
  }

  floatx4 o[4];
  float mr[4], lsum[4];
  floatx4 zero4 = {0.f, 0.f, 0.f, 0.f};
#pragma unroll
  for (int i = 0; i < 4; i++) o[i] = zero4;
#pragma unroll
  for (int i = 0; i < 4; i++) { mr[i] = -1e30f; lsum[i] = 0.f; }

  for (int kt = 0; kt < 16; kt++) {
    const int k0 = kt * 128;
    __syncthreads();
    for (int u = tid; u < 1024; u += 256) {
      int row = u >> 3;
      int c = (u & 7) * 8;
      *reinterpret_cast<float4*>(&Ks[row][c]) =
          *reinterpret_cast<const float4*>(Kbuf + hb + (size_t)(k0 + row) * 64 + c);
    }
    for (int u = tid; u < 1024; u += 256) {
      int d = u >> 4;
      int c = (u & 15) * 8;
      *reinterpret_cast<float4*>(&Vs[d][c]) =
          *reinterpret_cast<const float4*>(Vt + hb + (size_t)d * 2048 + k0 + c);
    }
    __syncthreads();

    // S = Q K^T * 0.125 (this wave's 16 q-rows x 128 keys)
    bf16x8 aq0 = *reinterpret_cast<const bf16x8*>(&Qs[w * 16 + lr][lq * 8]);
    bf16x8 aq1 = *reinterpret_cast<const bf16x8*>(&Qs[w * 16 + lr][32 + lq * 8]);
    floatx4 sf[8];
#pragma unroll
    for (int nt = 0; nt < 8; nt++) {
      floatx4 z = zero4;
      bf16x8 b0 = *reinterpret_cast<const bf16x8*>(&Ks[nt * 16 + lr][lq * 8]);
      bf16x8 b1 = *reinterpret_cast<const bf16x8*>(&Ks[nt * 16 + lr][32 + lq * 8]);
      z = __builtin_amdgcn_mfma_f32_16x16x32_bf16(aq0, b0, z, 0, 0, 0);
      z = __builtin_amdgcn_mfma_f32_16x16x32_bf16(aq1, b1, z, 0, 0, 0);
      sf[nt] = z * 0.125f;
    }

    // online softmax: rows of this lane are (lq*4 + r)
    float mn[4], al[4];
#pragma unroll
    for (int r = 0; r < 4; r++) {
      float m = sf[0][r];
#pragma unroll
      for (int nt = 1; nt < 8; nt++) m = fmaxf(m, sf[nt][r]);
      m = fmaxf(m, __shfl_xor(m, 1, 64));
      m = fmaxf(m, __shfl_xor(m, 2, 64));
      m = fmaxf(m, __shfl_xor(m, 4, 64));
      m = fmaxf(m, __shfl_xor(m, 8, 64));
      mn[r] = fmaxf(mr[r], m);
      al[r] = __expf(mr[r] - mn[r]);
      mr[r] = mn[r];
    }
    float ls[4] = {0.f, 0.f, 0.f, 0.f};
#pragma unroll
    for (int nt = 0; nt < 8; nt++)
#pragma unroll
      for (int r = 0; r < 4; r++) {
        float p = __expf(sf[nt][r] - mn[r]);
        ls[r] += p;
        Ps[w][lq * 4 + r][nt * 16 + lr] = (bf16_t)p;
      }
#pragma unroll
    for (int r = 0; r < 4; r++) {
      float t = ls[r];
      t += __shfl_xor(t, 1, 64);
      t += __shfl_xor(t, 2, 64);
      t += __shfl_xor(t, 4, 64);
      t += __shfl_xor(t, 8, 64);
      lsum[r] = lsum[r] * al[r] + t;
      o[0][r] *= al[r];
      o[1][r] *= al[r];
      o[2][r] *= al[r];
      o[3][r] *= al[r];
    }
    __syncthreads();

    // O += P V  (A = P [16 x 128], B = Vt tile [d][key])
#pragma unroll
    for (int kk = 0; kk < 4; kk++) {
      bf16x8 ap = *reinterpret_cast<const bf16x8*>(&Ps[w][lr][kk * 32 + lq * 8]);
#pragma unroll
      for (int dt = 0; dt < 4; dt++) {
        bf16x8 bv_ = *reinterpret_cast<const bf16x8*>(&Vs[dt * 16 + lr][kk * 32 + lq * 8]);
        o[dt] = __builtin_amdgcn_mfma_f32_16x16x32_bf16(ap, bv_, o[dt], 0, 0, 0);
      }
    }
  }

  // epilogue: normalize, write Ctx [B,S,1024]
  const int b = bh >> 4;
  const int h = bh & 15;
#pragma unroll
  for (int dt = 0; dt < 4; dt++)
#pragma unroll
    for (int r = 0; r < 4; r++) {
      int srow = q0 + w * 16 + lq * 4 + r;
      float v = o[dt][r] / lsum[r];
      Ctx[((size_t)(b * 2048 + srow)) * 1024 + h * 64 + dt * 16 + lr] = (bf16_t)v;
    }
}

// ---------------------------------------------------------------------------
// Kernel 4: output projection + bias + gamma -> fp32 d_out.
// ---------------------------------------------------------------------------
__global__ __launch_bounds__(256) void oproj_kernel(
    const bf16_t* __restrict__ Ctx, const bf16_t* __restrict__ Wobf,
    const float* __restrict__ bo, const float* __restrict__ gamma,
    float* __restrict__ out) {
  const int m0 = blockIdx.x * 128;
  const int n0 = blockIdx.y * 128;
  floatx4 acc[4][4];
  floatx4 zero4 = {0.f, 0.f, 0.f, 0.f};
#pragma unroll
  for (int i = 0; i < 4; i++)
#pragma unroll
    for (int j = 0; j < 4; j++) acc[i][j] = zero4;

  gemm_tile_128(Ctx, Wobf, m0, n0, acc);

  const int lane = threadIdx.x & 63;
  const int wave = threadIdx.x >> 6;
  const int wm = (wave >> 1) * 64;
  const int wn = (wave & 1) * 64;
  const int lr = lane & 15;
  const int lq = lane >> 4;
#pragma unroll
  for (int i = 0; i < 4; i++)
#pragma unroll
    for (int j = 0; j < 4; j++)
#pragma unroll
      for (int r = 0; r < 4; r++) {
        int m = m0 + wm + i * 16 + lq * 4 + r;
        int n = n0 + wn + j * 16 + lr;
        out[(size_t)m * 1024 + n] = gamma[n] * (acc[i][j][r] + bo[n]);
      }
}

// ---------------------------------------------------------------------------
extern "C" void kernel_launch(void* const* d_in, const int* in_sizes, int n_in,
                              void* d_out, int out_size, void* d_ws,
                              size_t ws_size, hipStream_t stream) {
  const float* query = (const float*)d_in[0];
  const float* Wq = (const float*)d_in[1];
  const float* bq = (const float*)d_in[2];
  const float* Wk = (const float*)d_in[3];
  const float* bk = (const float*)d_in[4];
  const float* Wv = (const float*)d_in[5];
  const float* bv = (const float*)d_in[6];
  const float* Wo = (const float*)d_in[7];
  const float* bo = (const float*)d_in[8];
  const float* gamma = (const float*)d_in[9];
  float* out = (float*)d_out;

  char* ws = (char*)d_ws;
  bf16_t* Xbf  = (bf16_t*)(ws);
  bf16_t* Wqkv = (bf16_t*)(ws + (8ull << 20));
  bf16_t* Wobf = (bf16_t*)(ws + (14ull << 20));
  bf16_t* Qbuf = (bf16_t*)(ws + (16ull << 20));
  bf16_t* Kbuf = (bf16_t*)(ws + (24ull << 20));
  bf16_t* Vt   = (bf16_t*)(ws + (32ull << 20));
  bf16_t* Ctx  = (bf16_t*)(ws + (40ull << 20));

  convert_kernel<<<dim3(8192), dim3(256), 0, stream>>>(query, Wq, Wk, Wv, Wo,
                                                       Xbf, Wqkv, Wobf);
  qkv_kernel<<<dim3(32, 8, 3), dim3(256), 0, stream>>>(Xbf, Wqkv, bq, bk, bv,
                                                       Qbuf, Kbuf, Vt);
  rope_kernel<<<dim3(16384), dim3(256), 0, stream>>>(Qbuf, Kbuf);
  attn_kernel<<<dim3(32, 32), dim3(256), 0, stream>>>(Qbuf, Kbuf, Vt, Ctx);
  oproj_kernel<<<dim3(32, 8), dim3(256), 0, stream>>>(Ctx, Wobf, bo, gamma, out);
}

// Round 2
// 224.660 us; speedup vs baseline: 1.4691x; 1.4691x over previous
//
#include <hip/hip_runtime.h>
#include <hip/hip_bf16.h>
#include <math.h>

typedef __bf16 bf16_t;
typedef __bf16 bf16x8 __attribute__((ext_vector_type(8)));
typedef float floatx4 __attribute__((ext_vector_type(4)));

#define SC_QK 0.18033688011112042f  // 0.125 * log2(e)

__device__ __forceinline__ float fast_exp2(float x) {
#if __has_builtin(__builtin_amdgcn_exp2f)
  return __builtin_amdgcn_exp2f(x);
#else
  return exp2f(x);
#endif
}

// async global->LDS, 16B per lane; lptr must be wave-uniform (lane i lands at
// lptr + 16*i).
__device__ __forceinline__ void async_load16(const bf16_t* g, bf16_t* l) {
  __builtin_amdgcn_global_load_lds(
      (__attribute__((address_space(1))) void*)(void*)g,
      (__attribute__((address_space(3))) void*)l, 16, 0, 0);
}

// ---------------------------------------------------------------------------
// Kernel 0: fp32 -> bf16 conversion of query + all 4 weight matrices.
// ---------------------------------------------------------------------------
__global__ __launch_bounds__(256) void convert_kernel(
    const float* __restrict__ query, const float* __restrict__ Wq,
    const float* __restrict__ Wk, const float* __restrict__ Wv,
    const float* __restrict__ Wo, bf16_t* __restrict__ Xbf,
    bf16_t* __restrict__ Wqkv, bf16_t* __restrict__ Wobf) {
  long base = ((long)blockIdx.x * 256 + threadIdx.x) * 4;
  const float* src;
  bf16_t* dst;
  long off;
  if (base < 4194304L)      { src = query; dst = Xbf;             off = base; }
  else if (base < 5242880L) { src = Wq;    dst = Wqkv;            off = base - 4194304L; }
  else if (base < 6291456L) { src = Wk;    dst = Wqkv + 1048576;  off = base - 5242880L; }
  else if (base < 7340032L) { src = Wv;    dst = Wqkv + 2097152;  off = base - 6291456L; }
  else                      { src = Wo;    dst = Wobf;            off = base - 7340032L; }
  float4 v = *reinterpret_cast<const float4*>(src + off);
  dst[off + 0] = (bf16_t)v.x;
  dst[off + 1] = (bf16_t)v.y;
  dst[off + 2] = (bf16_t)v.z;
  dst[off + 3] = (bf16_t)v.w;
}

// ---------------------------------------------------------------------------
// 128x128 bf16 MFMA GEMM tile, m97-style async staging.
// LDS tiles packed [128][32] (64B rows: frag-read start banks spread by row
// parity -> b128 floor, no conflicts). BK=32, 32 k-steps.
// ---------------------------------------------------------------------------
__device__ __forceinline__ void gemm_tile_async(const bf16_t* __restrict__ A,
                                                const bf16_t* __restrict__ Bn,
                                                int m0, int n0,
                                                floatx4 acc[4][4]) {
  __shared__ __align__(16) bf16_t As[128 * 32];
  __shared__ __align__(16) bf16_t Bs[128 * 32];
  const int tid = threadIdx.x;
  const int lane = tid & 63;
  const int wave = tid >> 6;
  const int wm = (wave >> 1) * 64;
  const int wn = (wave & 1) * 64;
  const int lr = lane & 15;
  const int lq = lane >> 4;
  const int srow = lane >> 2;       // row within 16-row staging instr
  const int scol = (lane & 3) * 8;  // element col within 32

  for (int kk = 0; kk < 1024; kk += 32) {
    __syncthreads();
#pragma unroll
    for (int u = 0; u < 2; u++) {
      int t = wave * 2 + u;  // 0..7
      int row = t * 16 + srow;
      async_load16(A + (size_t)(m0 + row) * 1024 + kk + scol, &As[t * 512]);
      async_load16(Bn + (size_t)(n0 + row) * 1024 + kk + scol, &Bs[t * 512]);
    }
    __syncthreads();
    bf16x8 af[4], bfr[4];
#pragma unroll
    for (int i = 0; i < 4; i++)
      af[i] = *reinterpret_cast<const bf16x8*>(&As[(wm + i * 16 + lr) * 32 + lq * 8]);
#pragma unroll
    for (int j = 0; j < 4; j++)
      bfr[j] = *reinterpret_cast<const bf16x8*>(&Bs[(wn + j * 16 + lr) * 32 + lq * 8]);
#pragma unroll
    for (int i = 0; i < 4; i++)
#pragma unroll
      for (int j = 0; j < 4; j++)
        acc[i][j] = __builtin_amdgcn_mfma_f32_16x16x32_bf16(af[i], bfr[j],
                                                            acc[i][j], 0, 0, 0);
  }
}

// ---------------------------------------------------------------------------
// Kernel 1: QKV projection with fused bias + RoPE (for Q,K).
// Q pre-scaled by 0.125*log2e (softmax runs in log2 domain).
// Q,K -> [B,H,S,dh] bf16; V -> Vt [B,H,dh,S] bf16.
// ---------------------------------------------------------------------------
__global__ __launch_bounds__(256, 3) void qkv_kernel(
    const bf16_t* __restrict__ Xbf, const bf16_t* __restrict__ Wqkv,
    const float* __restrict__ bq, const float* __restrict__ bk,
    const float* __restrict__ bv, bf16_t* __restrict__ Qbuf,
    bf16_t* __restrict__ Kbuf, bf16_t* __restrict__ Vt) {
  const int m0 = blockIdx.x * 128;
  const int n0 = blockIdx.y * 128;
  const int z = blockIdx.z;
  floatx4 acc[4][4];
  floatx4 zero4 = {0.f, 0.f, 0.f, 0.f};
#pragma unroll
  for (int i = 0; i < 4; i++)
#pragma unroll
    for (int j = 0; j < 4; j++) acc[i][j] = zero4;

  gemm_tile_async(Xbf, Wqkv + (size_t)z * 1048576, m0, n0, acc);

  const int lane = threadIdx.x & 63;
  const int wave = threadIdx.x >> 6;
  const int wm = (wave >> 1) * 64;
  const int wn = (wave & 1) * 64;
  const int lr = lane & 15;
  const int lq = lane >> 4;
  const int h = (n0 + wn) >> 6;  // each wave's 64 features = one head

  if (z == 2) {
#pragma unroll
    for (int i = 0; i < 4; i++)
#pragma unroll
      for (int j = 0; j < 4; j++)
#pragma unroll
        for (int r = 0; r < 4; r++) {
          int m = m0 + wm + i * 16 + lq * 4 + r;
          int n = n0 + wn + j * 16 + lr;
          float v = acc[i][j][r] + bv[n];
          int b = m >> 11, s = m & 2047;
          int d = n & 63;
          Vt[((size_t)(b * 16 + h) * 64 + d) * 2048 + s] = (bf16_t)v;
        }
  } else {
    bf16_t* dst = (z == 0) ? Qbuf : Kbuf;
    const float* bias = (z == 0) ? bq : bk;
    const float sc = (z == 0) ? SC_QK : 1.0f;
#pragma unroll
    for (int i = 0; i < 4; i++)
#pragma unroll
      for (int r = 0; r < 4; r++) {
        int m = m0 + wm + i * 16 + lq * 4 + r;
        int b = m >> 11, s = m & 2047;
        size_t rowbase = ((size_t)(b * 16 + h) * 2048 + s) * 64;
#pragma unroll
        for (int jj = 0; jj < 2; jj++) {
          int d1 = jj * 16 + lr;  // 0..31
          int n1 = n0 + wn + d1;
          float x1 = acc[i][jj][r] + bias[n1];
          float x2 = acc[i][jj + 2][r] + bias[n1 + 32];
          // inv_freq = 10000^(-d1/32); ln(10000)/32 = 0.28782313662425576
          float invf = __expf(-(float)d1 * 0.28782313662425576f);
          float ang = (float)s * invf;
          float c, sn;
          sincosf(ang, &sn, &c);
          dst[rowbase + d1]      = (bf16_t)((x1 * c - x2 * sn) * sc);
          dst[rowbase + d1 + 32] = (bf16_t)((x2 * c + x1 * sn) * sc);
        }
      }
  }
}

// ---------------------------------------------------------------------------
// Kernel 3: flash attention. 512 threads = 8 waves; 128 q-rows/block (16 per
// wave); 128-key tiles. K/V staged via global_load_lds into packed XOR-
// swizzled LDS. Softmax in log2 domain (Q pre-scaled). LDS 66KB -> 2 blk/CU.
// ---------------------------------------------------------------------------
__global__ __launch_bounds__(512, 4) void attn_kernel(
    const bf16_t* __restrict__ Qbuf, const bf16_t* __restrict__ Kbuf,
    const bf16_t* __restrict__ Vt, bf16_t* __restrict__ Ctx) {
  __shared__ __align__(16) bf16_t Ks[128 * 64];   // [key][d], swizzled 16B blks
  __shared__ __align__(16) bf16_t Vs[64 * 128];   // [d][key], swizzled 16B blks
  __shared__ __align__(16) bf16_t Ps[8][16][136]; // per-wave P
  const int tid = threadIdx.x;
  const int lane = tid & 63;
  const int w = tid >> 6;  // 0..7
  const int lr = lane & 15;
  const int lq = lane >> 4;
  const int q0 = blockIdx.x * 128;
  const int bh = blockIdx.y;
  const size_t hb = (size_t)bh * (2048 * 64);

  // Q frags: loop-invariant, direct from global
  const bf16_t* qp = Qbuf + hb + (size_t)(q0 + w * 16 + lr) * 64 + lq * 8;
  bf16x8 aq0 = *reinterpret_cast<const bf16x8*>(qp);
  bf16x8 aq1 = *reinterpret_cast<const bf16x8*>(qp + 32);

  floatx4 o[4];
  float mr[4], lsum[4];
  floatx4 zero4 = {0.f, 0.f, 0.f, 0.f};
#pragma unroll
  for (int i = 0; i < 4; i++) o[i] = zero4;
#pragma unroll
  for (int i = 0; i < 4; i++) { mr[i] = -1e30f; lsum[i] = 0.f; }

  // staging lane->address precompute
  const int krow_l = lane >> 3;          // 0..7 within 8-row K instr
  const int kblk_l = lane & 7;           // phys 16B block within K row
  const int vrow_l = lane >> 4;          // 0..3 within 4-row V instr
  const int vblk_l = lane & 15;          // phys 16B block within V row

  for (int kt = 0; kt < 16; kt++) {
    const int k0 = kt * 128;
    __syncthreads();
#pragma unroll
    for (int u = 0; u < 2; u++) {
      int t = w * 2 + u;  // 0..15
      {  // K rows t*8 .. t*8+7 (64 bf16 = 8 phys blocks each)
        int r = t * 8 + krow_l;
        int c = kblk_l ^ (r & 7);  // logical block fetched into phys slot
        async_load16(Kbuf + hb + (size_t)(k0 + r) * 64 + c * 8, &Ks[t * 512]);
      }
      {  // V rows t*4 .. t*4+3 (128 bf16 = 16 phys blocks each)
        int d = t * 4 + vrow_l;
        int c = vblk_l ^ (d & 15);
        async_load16(Vt + hb + (size_t)d * 2048 + k0 + c * 8, &Vs[t * 512]);
      }
    }
    __syncthreads();

    // S = Q K^T (log2-scaled; Q carries 0.125*log2e)
    floatx4 sf[8];
#pragma unroll
    for (int nt = 0; nt < 8; nt++) {
      int krow = nt * 16 + lr;
      bf16x8 b0 = *reinterpret_cast<const bf16x8*>(
          &Ks[krow * 64 + (lq ^ (krow & 7)) * 8]);
      bf16x8 b1 = *reinterpret_cast<const bf16x8*>(
          &Ks[krow * 64 + (((4 + lq)) ^ (krow & 7)) * 8]);
      floatx4 z4 = zero4;
      z4 = __builtin_amdgcn_mfma_f32_16x16x32_bf16(aq0, b0, z4, 0, 0, 0);
      z4 = __builtin_amdgcn_mfma_f32_16x16x32_bf16(aq1, b1, z4, 0, 0, 0);
      sf[nt] = z4;
    }

    // online softmax (log2 domain)
    float mn_[4], al[4];
#pragma unroll
    for (int r = 0; r < 4; r++) {
      float m = sf[0][r];
#pragma unroll
      for (int nt = 1; nt < 8; nt++) m = fmaxf(m, sf[nt][r]);
      m = fmaxf(m, __shfl_xor(m, 1, 64));
      m = fmaxf(m, __shfl_xor(m, 2, 64));
      m = fmaxf(m, __shfl_xor(m, 4, 64));
      m = fmaxf(m, __shfl_xor(m, 8, 64));
      mn_[r] = fmaxf(mr[r], m);
      al[r] = fast_exp2(mr[r] - mn_[r]);
      mr[r] = mn_[r];
    }
    float ls[4] = {0.f, 0.f, 0.f, 0.f};
#pragma unroll
    for (int nt = 0; nt < 8; nt++)
#pragma unroll
      for (int r = 0; r < 4; r++) {
        float p = fast_exp2(sf[nt][r] - mn_[r]);
        ls[r] += p;
        Ps[w][lq * 4 + r][nt * 16 + lr] = (bf16_t)p;
      }
#pragma unroll
    for (int r = 0; r < 4; r++) {
      float t = ls[r];
      t += __shfl_xor(t, 1, 64);
      t += __shfl_xor(t, 2, 64);
      t += __shfl_xor(t, 4, 64);
      t += __shfl_xor(t, 8, 64);
      lsum[r] = lsum[r] * al[r] + t;
      o[0][r] *= al[r];
      o[1][r] *= al[r];
      o[2][r] *= al[r];
      o[3][r] *= al[r];
    }

    // O += P V   (Ps same-wave write->read, ordered by lgkmcnt; no barrier)
#pragma unroll
    for (int kk = 0; kk < 4; kk++) {
      bf16x8 ap = *reinterpret_cast<const bf16x8*>(&Ps[w][lr][kk * 32 + lq * 8]);
#pragma unroll
      for (int dt = 0; dt < 4; dt++) {
        int d = dt * 16 + lr;
        bf16x8 bv_ = *reinterpret_cast<const bf16x8*>(
            &Vs[d * 128 + (((kk * 4 + lq)) ^ (d & 15)) * 8]);
        o[dt] = __builtin_amdgcn_mfma_f32_16x16x32_bf16(ap, bv_, o[dt], 0, 0, 0);
      }
    }
  }

  // epilogue
  const int b = bh >> 4;
  const int h = bh & 15;
#pragma unroll
  for (int r = 0; r < 4; r++) {
    float inv_l = 1.0f / lsum[r];
    int srow = q0 + w * 16 + lq * 4 + r;
#pragma unroll
    for (int dt = 0; dt < 4; dt++) {
      Ctx[((size_t)(b * 2048 + srow)) * 1024 + h * 64 + dt * 16 + lr] =
          (bf16_t)(o[dt][r] * inv_l);
    }
  }
}

// ---------------------------------------------------------------------------
// Kernel 4: output projection + bias + gamma -> fp32 d_out.
// ---------------------------------------------------------------------------
__global__ __launch_bounds__(256, 3) void oproj_kernel(
    const bf16_t* __restrict__ Ctx, const bf16_t* __restrict__ Wobf,
    const float* __restrict__ bo, const float* __restrict__ gamma,
    float* __restrict__ out) {
  const int m0 = blockIdx.x * 128;
  const int n0 = blockIdx.y * 128;
  floatx4 acc[4][4];
  floatx4 zero4 = {0.f, 0.f, 0.f, 0.f};
#pragma unroll
  for (int i = 0; i < 4; i++)
#pragma unroll
    for (int j = 0; j < 4; j++) acc[i][j] = zero4;

  gemm_tile_async(Ctx, Wobf, m0, n0, acc);

  const int lane = threadIdx.x & 63;
  const int wave = threadIdx.x >> 6;
  const int wm = (wave >> 1) * 64;
  const int wn = (wave & 1) * 64;
  const int lr = lane & 15;
  const int lq = lane >> 4;
#pragma unroll
  for (int i = 0; i < 4; i++)
#pragma unroll
    for (int j = 0; j < 4; j++)
#pragma unroll
      for (int r = 0; r < 4; r++) {
        int m = m0 + wm + i * 16 + lq * 4 + r;
        int n = n0 + wn + j * 16 + lr;
        out[(size_t)m * 1024 + n] = gamma[n] * (acc[i][j][r] + bo[n]);
      }
}

// ---------------------------------------------------------------------------
extern "C" void kernel_launch(void* const* d_in, const int* in_sizes, int n_in,
                              void* d_out, int out_size, void* d_ws,
                              size_t ws_size, hipStream_t stream) {
  const float* query = (const float*)d_in[0];
  const float* Wq = (const float*)d_in[1];
  const float* bq = (const float*)d_in[2];
  const float* Wk = (const float*)d_in[3];
  const float* bk = (const float*)d_in[4];
  const float* Wv = (const float*)d_in[5];
  const float* bv = (const float*)d_in[6];
  const float* Wo = (const float*)d_in[7];
  const float* bo = (const float*)d_in[8];
  const float* gamma = (const float*)d_in[9];
  float* out = (float*)d_out;

  char* ws = (char*)d_ws;
  bf16_t* Xbf  = (bf16_t*)(ws);
  bf16_t* Wqkv = (bf16_t*)(ws + (8ull << 20));
  bf16_t* Wobf = (bf16_t*)(ws + (14ull << 20));
  bf16_t* Qbuf = (bf16_t*)(ws + (16ull << 20));
  bf16_t* Kbuf = (bf16_t*)(ws + (24ull << 20));
  bf16_t* Vt   = (bf16_t*)(ws + (32ull << 20));
  bf16_t* Ctx  = (bf16_t*)(ws + (40ull << 20));

  convert_kernel<<<dim3(8192), dim3(256), 0, stream>>>(query, Wq, Wk, Wv, Wo,
                                                       Xbf, Wqkv, Wobf);
  qkv_kernel<<<dim3(32, 8, 3), dim3(256), 0, stream>>>(Xbf, Wqkv, bq, bk, bv,
                                                       Qbuf, Kbuf, Vt);
  attn_kernel<<<dim3(16, 32), dim3(512), 0, stream>>>(Qbuf, Kbuf, Vt, Ctx);
  oproj_kernel<<<dim3(32, 8), dim3(256), 0, stream>>>(Ctx, Wobf, bo, gamma, out);
}

// Round 4
// 221.084 us; speedup vs baseline: 1.4928x; 1.0162x over previous
//
#include <hip/hip_runtime.h>
#include <hip/hip_bf16.h>
#include <math.h>

typedef __bf16 bf16_t;
typedef __bf16 bf16x8 __attribute__((ext_vector_type(8)));
typedef __bf16 bf16x4 __attribute__((ext_vector_type(4)));
typedef short short4v __attribute__((ext_vector_type(4)));
typedef float floatx4 __attribute__((ext_vector_type(4)));

#define SC_QK 0.18033688011112042f  // 0.125 * log2(e)

__device__ __forceinline__ float fast_exp2(float x) {
#if __has_builtin(__builtin_amdgcn_exp2f)
  return __builtin_amdgcn_exp2f(x);
#else
  return exp2f(x);
#endif
}

// async global->LDS, 16B per lane; LDS base wave-uniform, lane i -> base+16i.
__device__ __forceinline__ void async_load16(const bf16_t* g, bf16_t* l) {
  __builtin_amdgcn_global_load_lds(
      (__attribute__((address_space(1))) void*)(void*)g,
      (__attribute__((address_space(3))) void*)l, 16, 0, 0);
}

// PV matmul piece: D = A(V^T frag) * B(P^T frag) + C, K=16.
__device__ __forceinline__ floatx4 mfma_pv(bf16x4 vfrag, bf16x4 pfrag,
                                           floatx4 acc) {
#if __has_builtin(__builtin_amdgcn_mfma_f32_16x16x16bf16_1k)
  return __builtin_amdgcn_mfma_f32_16x16x16bf16_1k(
      __builtin_bit_cast(short4v, vfrag), __builtin_bit_cast(short4v, pfrag),
      acc, 0, 0, 0);
#else
  const bf16_t z = (bf16_t)0.0f;
  bf16x8 a = {vfrag[0], vfrag[1], vfrag[2], vfrag[3], z, z, z, z};
  bf16x8 b = {pfrag[0], pfrag[1], pfrag[2], pfrag[3], z, z, z, z};
  return __builtin_amdgcn_mfma_f32_16x16x32_bf16(a, b, acc, 0, 0, 0);
#endif
}

// ---------------------------------------------------------------------------
// Kernel 0: fp32 -> bf16 conversion of query + all 4 weight matrices.
// ---------------------------------------------------------------------------
__global__ __launch_bounds__(256) void convert_kernel(
    const float* __restrict__ query, const float* __restrict__ Wq,
    const float* __restrict__ Wk, const float* __restrict__ Wv,
    const float* __restrict__ Wo, bf16_t* __restrict__ Xbf,
    bf16_t* __restrict__ Wqkv, bf16_t* __restrict__ Wobf) {
  long base = ((long)blockIdx.x * 256 + threadIdx.x) * 4;
  const float* src;
  bf16_t* dst;
  long off;
  if (base < 4194304L)      { src = query; dst = Xbf;             off = base; }
  else if (base < 5242880L) { src = Wq;    dst = Wqkv;            off = base - 4194304L; }
  else if (base < 6291456L) { src = Wk;    dst = Wqkv + 1048576;  off = base - 5242880L; }
  else if (base < 7340032L) { src = Wv;    dst = Wqkv + 2097152;  off = base - 6291456L; }
  else                      { src = Wo;    dst = Wobf;            off = base - 7340032L; }
  float4 v = *reinterpret_cast<const float4*>(src + off);
  dst[off + 0] = (bf16_t)v.x;
  dst[off + 1] = (bf16_t)v.y;
  dst[off + 2] = (bf16_t)v.z;
  dst[off + 3] = (bf16_t)v.w;
}

// ---------------------------------------------------------------------------
// Kernel 0b: RoPE cos/sin table [2][2048][32] fp32 (lives in the Ctx region;
// consumed by qkv, then attn fully overwrites Ctx).
// ---------------------------------------------------------------------------
__global__ __launch_bounds__(256) void rope_tab_kernel(float* __restrict__ tab) {
  int idx = blockIdx.x * 256 + threadIdx.x;  // [0, 65536)
  int s = idx >> 5;
  int p = idx & 31;
  float invf = __expf(-(float)p * 0.28782313662425576f);
  float ang = (float)s * invf;
  float c, sn;
  sincosf(ang, &sn, &c);
  tab[idx] = c;
  tab[65536 + idx] = sn;
}

// ---------------------------------------------------------------------------
// 128x128 bf16 MFMA GEMM tile, m97-style async staging, packed [128][32] LDS.
// ---------------------------------------------------------------------------
__device__ __forceinline__ void gemm_tile_async(const bf16_t* __restrict__ A,
                                                const bf16_t* __restrict__ Bn,
                                                int m0, int n0,
                                                floatx4 acc[4][4]) {
  __shared__ __align__(16) bf16_t As[128 * 32];
  __shared__ __align__(16) bf16_t Bs[128 * 32];
  const int tid = threadIdx.x;
  const int lane = tid & 63;
  const int wave = tid >> 6;
  const int wm = (wave >> 1) * 64;
  const int wn = (wave & 1) * 64;
  const int lr = lane & 15;
  const int lq = lane >> 4;
  const int srow = lane >> 2;       // row within 16-row staging instr
  const int scol = (lane & 3) * 8;  // element col within 32

  for (int kk = 0; kk < 1024; kk += 32) {
    __syncthreads();
#pragma unroll
    for (int u = 0; u < 2; u++) {
      int t = wave * 2 + u;  // 0..7
      int row = t * 16 + srow;
      async_load16(A + (size_t)(m0 + row) * 1024 + kk + scol, &As[t * 512]);
      async_load16(Bn + (size_t)(n0 + row) * 1024 + kk + scol, &Bs[t * 512]);
    }
    __syncthreads();
    bf16x8 af[4], bfr[4];
#pragma unroll
    for (int i = 0; i < 4; i++)
      af[i] = *reinterpret_cast<const bf16x8*>(&As[(wm + i * 16 + lr) * 32 + lq * 8]);
#pragma unroll
    for (int j = 0; j < 4; j++)
      bfr[j] = *reinterpret_cast<const bf16x8*>(&Bs[(wn + j * 16 + lr) * 32 + lq * 8]);
#pragma unroll
    for (int i = 0; i < 4; i++)
#pragma unroll
      for (int j = 0; j < 4; j++)
        acc[i][j] = __builtin_amdgcn_mfma_f32_16x16x32_bf16(af[i], bfr[j],
                                                            acc[i][j], 0, 0, 0);
  }
}

// ---------------------------------------------------------------------------
// Kernel 1: QKV projection with fused bias + RoPE (table-based) for Q,K.
// Q pre-scaled by 0.125*log2e. Q,K -> [B,H,S,dh]; V -> Vt [B,H,dh,S].
// ---------------------------------------------------------------------------
__global__ __launch_bounds__(256, 3) void qkv_kernel(
    const bf16_t* __restrict__ Xbf, const bf16_t* __restrict__ Wqkv,
    const float* __restrict__ bq, const float* __restrict__ bk,
    const float* __restrict__ bv, const float* __restrict__ Tab,
    bf16_t* __restrict__ Qbuf, bf16_t* __restrict__ Kbuf,
    bf16_t* __restrict__ Vt) {
  const int m0 = blockIdx.x * 128;
  const int n0 = blockIdx.y * 128;
  const int z = blockIdx.z;
  floatx4 acc[4][4];
  floatx4 zero4 = {0.f, 0.f, 0.f, 0.f};
#pragma unroll
  for (int i = 0; i < 4; i++)
#pragma unroll
    for (int j = 0; j < 4; j++) acc[i][j] = zero4;

  gemm_tile_async(Xbf, Wqkv + (size_t)z * 1048576, m0, n0, acc);

  const int lane = threadIdx.x & 63;
  const int wave = threadIdx.x >> 6;
  const int wm = (wave >> 1) * 64;
  const int wn = (wave & 1) * 64;
  const int lr = lane & 15;
  const int lq = lane >> 4;
  const int h = (n0 + wn) >> 6;  // each wave's 64 features = one head

  if (z == 2) {
#pragma unroll
    for (int i = 0; i < 4; i++)
#pragma unroll
      for (int j = 0; j < 4; j++)
#pragma unroll
        for (int r = 0; r < 4; r++) {
          int m = m0 + wm + i * 16 + lq * 4 + r;
          int n = n0 + wn + j * 16 + lr;
          float v = acc[i][j][r] + bv[n];
          int b = m >> 11, s = m & 2047;
          int d = n & 63;
          Vt[((size_t)(b * 16 + h) * 64 + d) * 2048 + s] = (bf16_t)v;
        }
  } else {
    bf16_t* dst = (z == 0) ? Qbuf : Kbuf;
    const float* bias = (z == 0) ? bq : bk;
    const float sc = (z == 0) ? SC_QK : 1.0f;
#pragma unroll
    for (int i = 0; i < 4; i++)
#pragma unroll
      for (int r = 0; r < 4; r++) {
        int m = m0 + wm + i * 16 + lq * 4 + r;
        int b = m >> 11, s = m & 2047;
        size_t rowbase = ((size_t)(b * 16 + h) * 2048 + s) * 64;
#pragma unroll
        for (int jj = 0; jj < 2; jj++) {
          int d1 = jj * 16 + lr;  // 0..31
          int n1 = n0 + wn + d1;
          float x1 = acc[i][jj][r] + bias[n1];
          float x2 = acc[i][jj + 2][r] + bias[n1 + 32];
          float c = Tab[s * 32 + d1];
          float sn = Tab[65536 + s * 32 + d1];
          dst[rowbase + d1]      = (bf16_t)((x1 * c - x2 * sn) * sc);
          dst[rowbase + d1 + 32] = (bf16_t)((x2 * c + x1 * sn) * sc);
        }
      }
  }
}

// ---------------------------------------------------------------------------
// Kernel 3: flash attention, transposed (S^T = K Q^T, O^T = V^T P^T).
// 256 threads = 4 waves; each wave owns 32 q rows (2 groups of 16), one q
// per lane per group. P^T feeds K=16 PV MFMAs straight from registers (no
// LDS for P). K/V tiles of 128 keys staged via global_load_lds into XOR-
// swizzled packed LDS (16 KB). Epilogue: direct bf16x4 stores (full Ctx
// coverage -- the round-3 gap bug left Tab floats in Ctx whose low halves
// are bf16 NaN patterns).
// ---------------------------------------------------------------------------
__global__ __launch_bounds__(256, 3) void attn_kernel(
    const bf16_t* __restrict__ Qbuf, const bf16_t* __restrict__ Kbuf,
    const bf16_t* __restrict__ Vt, bf16_t* __restrict__ Ctx) {
  __shared__ __align__(16) bf16_t Sh[16384];  // Ks[128*64] | Vs[64*128]
  bf16_t* Ks = Sh;
  bf16_t* Vs = Sh + 8192;
  const int tid = threadIdx.x;
  const int lane = tid & 63;
  const int w = tid >> 6;   // 0..3
  const int lr = lane & 15;
  const int lq = lane >> 4; // 0..3
  const int q0 = blockIdx.x * 128;
  const int bh = blockIdx.y;
  const size_t hb = (size_t)bh * (2048 * 64);
  const int qw = q0 + w * 32;

  // Q B-frags (loop-invariant): 2 groups x 2 k-halves (d 0..31 / 32..63)
  bf16x8 qf[2][2];
#pragma unroll
  for (int g = 0; g < 2; g++) {
    const bf16_t* qp = Qbuf + hb + (size_t)(qw + g * 16 + lr) * 64 + lq * 8;
    qf[g][0] = *reinterpret_cast<const bf16x8*>(qp);
    qf[g][1] = *reinterpret_cast<const bf16x8*>(qp + 32);
  }

  floatx4 o[2][4];  // O^T accum: lane holds q=lr, d=dt*16+lq*4+r
  float mr[2], lsum[2];
  floatx4 zero4 = {0.f, 0.f, 0.f, 0.f};
#pragma unroll
  for (int g = 0; g < 2; g++) {
    mr[g] = -1e30f;
    lsum[g] = 0.f;
#pragma unroll
    for (int dt = 0; dt < 4; dt++) o[g][dt] = zero4;
  }

  const int ksr = lane >> 3;   // K staging row within 8
  const int ksb = lane & 7;    // K staging phys 16B block
  const int vsr = lane >> 4;   // V staging row within 4
  const int vsb = lane & 15;   // V staging phys 16B block

  for (int kt = 0; kt < 16; kt++) {
    const int k0 = kt * 128;
    __syncthreads();
#pragma unroll
    for (int u = 0; u < 4; u++) {
      int t = w * 4 + u;  // 0..15
      {  // K rows t*8..t*8+7 (8 blocks each), swizzle blk^(row&7)
        int r = t * 8 + ksr;
        int c = ksb ^ (r & 7);
        async_load16(Kbuf + hb + (size_t)(k0 + r) * 64 + c * 8, Ks + t * 512);
      }
      {  // V rows t*4..t*4+3 (16 blocks each), swizzle blk^(d&15)
        int d = t * 4 + vsr;
        int c = vsb ^ (d & 15);
        async_load16(Vt + hb + (size_t)d * 2048 + k0 + c * 8, Vs + t * 512);
      }
    }
    __syncthreads();

    // S^T = K Q^T : A = K-frag, B = Q-frag. Lane: col=q=lr, row=key=lq*4+r
    floatx4 sf[2][8];
#pragma unroll
    for (int nt = 0; nt < 8; nt++) {
      int krow = nt * 16 + lr;
      bf16x8 kf0 = *reinterpret_cast<const bf16x8*>(
          &Ks[krow * 64 + (lq ^ (krow & 7)) * 8]);
      bf16x8 kf1 = *reinterpret_cast<const bf16x8*>(
          &Ks[krow * 64 + ((4 + lq) ^ (krow & 7)) * 8]);
#pragma unroll
      for (int g = 0; g < 2; g++) {
        floatx4 z4 = zero4;
        z4 = __builtin_amdgcn_mfma_f32_16x16x32_bf16(kf0, qf[g][0], z4, 0, 0, 0);
        z4 = __builtin_amdgcn_mfma_f32_16x16x32_bf16(kf1, qf[g][1], z4, 0, 0, 0);
        sf[g][nt] = z4;
      }
    }

    // online softmax (log2 domain; Q carries 0.125*log2e). One q per lane.
    float mn_[2], al[2], ls[2];
#pragma unroll
    for (int g = 0; g < 2; g++) {
      floatx4 mv = sf[g][0];
#pragma unroll
      for (int nt = 1; nt < 8; nt++) {
#pragma unroll
        for (int r = 0; r < 4; r++) mv[r] = fmaxf(mv[r], sf[g][nt][r]);
      }
      float m = fmaxf(fmaxf(mv[0], mv[1]), fmaxf(mv[2], mv[3]));
      m = fmaxf(m, __shfl_xor(m, 16, 64));
      m = fmaxf(m, __shfl_xor(m, 32, 64));
      float mn = fmaxf(mr[g], m);
      al[g] = fast_exp2(mr[g] - mn);
      mr[g] = mn;
      mn_[g] = mn;
      ls[g] = 0.f;
#pragma unroll
      for (int dt = 0; dt < 4; dt++) o[g][dt] *= al[g];
    }

    // fused P-compute + PV: O^T += V^T P^T (K=16 MFMA, P from registers)
#pragma unroll
    for (int nt = 0; nt < 8; nt++) {
      bf16x4 vf[4];
#pragma unroll
      for (int dt = 0; dt < 4; dt++) {
        int d = dt * 16 + lr;
        int blk = (2 * nt + (lq >> 1)) ^ (d & 15);
        vf[dt] = *reinterpret_cast<const bf16x4*>(
            &Vs[d * 128 + blk * 8 + (lq & 1) * 4]);
      }
#pragma unroll
      for (int g = 0; g < 2; g++) {
        bf16x4 pg;
#pragma unroll
        for (int r = 0; r < 4; r++) {
          float pv = fast_exp2(sf[g][nt][r] - mn_[g]);
          ls[g] += pv;
          pg[r] = (bf16_t)pv;
        }
#pragma unroll
        for (int dt = 0; dt < 4; dt++)
          o[g][dt] = mfma_pv(vf[dt], pg, o[g][dt]);
      }
    }
#pragma unroll
    for (int g = 0; g < 2; g++) {
      float t = ls[g];
      t += __shfl_xor(t, 16, 64);
      t += __shfl_xor(t, 32, 64);
      lsum[g] = lsum[g] * al[g] + t;
    }
  }

  // epilogue: normalize + direct bf16x4 stores (full coverage, no LDS)
  const int b = bh >> 4;
  const int h = bh & 15;
#pragma unroll
  for (int g = 0; g < 2; g++) {
    float inv_l = 1.0f / lsum[g];
    size_t rowb = ((size_t)(b * 2048 + qw + g * 16 + lr)) * 1024 + h * 64;
#pragma unroll
    for (int dt = 0; dt < 4; dt++) {
      bf16x4 pk;
#pragma unroll
      for (int r = 0; r < 4; r++) pk[r] = (bf16_t)(o[g][dt][r] * inv_l);
      *reinterpret_cast<bf16x4*>(&Ctx[rowb + dt * 16 + lq * 4]) = pk;
    }
  }
}

// ---------------------------------------------------------------------------
// Kernel 4: output projection + bias + gamma -> fp32 d_out.
// ---------------------------------------------------------------------------
__global__ __launch_bounds__(256, 3) void oproj_kernel(
    const bf16_t* __restrict__ Ctx, const bf16_t* __restrict__ Wobf,
    const float* __restrict__ bo, const float* __restrict__ gamma,
    float* __restrict__ out) {
  const int m0 = blockIdx.x * 128;
  const int n0 = blockIdx.y * 128;
  floatx4 acc[4][4];
  floatx4 zero4 = {0.f, 0.f, 0.f, 0.f};
#pragma unroll
  for (int i = 0; i < 4; i++)
#pragma unroll
    for (int j = 0; j < 4; j++) acc[i][j] = zero4;

  gemm_tile_async(Ctx, Wobf, m0, n0, acc);

  const int lane = threadIdx.x & 63;
  const int wave = threadIdx.x >> 6;
  const int wm = (wave >> 1) * 64;
  const int wn = (wave & 1) * 64;
  const int lr = lane & 15;
  const int lq = lane >> 4;
#pragma unroll
  for (int i = 0; i < 4; i++)
#pragma unroll
    for (int j = 0; j < 4; j++)
#pragma unroll
      for (int r = 0; r < 4; r++) {
        int m = m0 + wm + i * 16 + lq * 4 + r;
        int n = n0 + wn + j * 16 + lr;
        out[(size_t)m * 1024 + n] = gamma[n] * (acc[i][j][r] + bo[n]);
      }
}

// ---------------------------------------------------------------------------
extern "C" void kernel_launch(void* const* d_in, const int* in_sizes, int n_in,
                              void* d_out, int out_size, void* d_ws,
                              size_t ws_size, hipStream_t stream) {
  const float* query = (const float*)d_in[0];
  const float* Wq = (const float*)d_in[1];
  const float* bq = (const float*)d_in[2];
  const float* Wk = (const float*)d_in[3];
  const float* bk = (const float*)d_in[4];
  const float* Wv = (const float*)d_in[5];
  const float* bv = (const float*)d_in[6];
  const float* Wo = (const float*)d_in[7];
  const float* bo = (const float*)d_in[8];
  const float* gamma = (const float*)d_in[9];
  float* out = (float*)d_out;

  char* ws = (char*)d_ws;
  bf16_t* Xbf  = (bf16_t*)(ws);
  bf16_t* Wqkv = (bf16_t*)(ws + (8ull << 20));
  bf16_t* Wobf = (bf16_t*)(ws + (14ull << 20));
  bf16_t* Qbuf = (bf16_t*)(ws + (16ull << 20));
  bf16_t* Kbuf = (bf16_t*)(ws + (24ull << 20));
  bf16_t* Vt   = (bf16_t*)(ws + (32ull << 20));
  bf16_t* Ctx  = (bf16_t*)(ws + (40ull << 20));
  float*  Tab  = (float*)(ws + (40ull << 20));  // aliases Ctx; dead before attn

  rope_tab_kernel<<<dim3(256), dim3(256), 0, stream>>>(Tab);
  convert_kernel<<<dim3(8192), dim3(256), 0, stream>>>(query, Wq, Wk, Wv, Wo,
                                                       Xbf, Wqkv, Wobf);
  qkv_kernel<<<dim3(32, 8, 3), dim3(256), 0, stream>>>(Xbf, Wqkv, bq, bk, bv,
                                                       Tab, Qbuf, Kbuf, Vt);
  attn_kernel<<<dim3(16, 32), dim3(256), 0, stream>>>(Qbuf, Kbuf, Vt, Ctx);
  oproj_kernel<<<dim3(32, 8), dim3(256), 0, stream>>>(Ctx, Wobf, bo, gamma, out);
}